// Round 1
// baseline (48.502 us; speedup 1.0000x reference)
//
#include <hip/hip_runtime.h>
#include <math.h>

// EdgeAwareLoss — nibble-SWAR, round 4: full fusion.
//
// Exactness arguments vs the JAX reference (validated absmax 0.0 in r1-r3):
//  - img = (t>0.5)*255, integer Sobel => m is a multiple of 255, so
//    (m>50)==(m>150): weak==strong, hysteresis loop is an immediate fixed
//    point => strong == cand. No iteration.
//  - In units of 255: gx,gy in [-4,4], |gx|+|gy| <= 6, so m fits a nibble and
//    SWAR compares ((x|8)-y)&8 are exact (values <= 7).
//  - Direction classes enumerated exactly over the integer grid:
//      horiz (ay < ax*tan22.5): ay==0&&ax>=1 || ay==1&&ax>=3
//      vert  (ay > ax*tan67.5): ax==0&&ay>=1 || ax==1&&ay>=3
//  - t in {0,1} => bce = -max(log(t?p:1-p), -100); 1-p exact for p>=0.5
//    (Sterbenz) and >=0.5 otherwise.
//
// Round-4 changes (r3 = 44.8us; edge_loss ran at only ~2.1 TB/s effective —
// latency-bound around barriers — while a serial 10.5us binarize pass ran
// in front of it):
//  - binarize pre-pass FUSED into stage 0: target halo (72x72) read directly
//    as aligned float4 pairs (648 tasks x 32B, coalesced), compare+pack to
//    nibbles in LDS. Kills the serial 64MB pass + packed round-trip.
//    (r2's fused attempt used strided SCALAR loads — that was the regression,
//    not fusion itself.)
//  - pred tile (16 px/thread = 4 float4 = 16 VGPR) prefetched at kernel
//    entry; loads fly concurrently with the target stream and are complete
//    by stage D, so the BCE tail does no waiting.

typedef unsigned long long u64;
typedef unsigned int u32;
typedef unsigned short u16;

#define NT 256
#define H_IMG 1024
#define W_IMG 1024

constexpr u64 K1 = 0x1111111111111111ULL;
constexpr u64 K7 = 0x7777777777777777ULL;
constexpr u64 K8 = 0x8888888888888888ULL;

__device__ __forceinline__ u64 geq8(u64 x, u64 y) { return ((x | K8) - y) & K8; }
__device__ __forceinline__ u64 gt8(u64 x, u64 y) { return K8 & ~((y | K8) - x); }

__global__ __launch_bounds__(NT)
void edge_loss_kernel(const float* __restrict__ pred,
                      const float* __restrict__ target,
                      float* __restrict__ partials)
{
    __shared__ u32 simg[72][11];   // nibble-packed binarized target (q<=10)
    __shared__ u64 mw[70][6];      // m (nibbles, <=6); word5 zero
    __shared__ u64 clw[70][6];     // class nibbles: bit0=horiz bit1=vert bit2=sd
    __shared__ u16 ssw[68][5];     // strong, 16 px bitmasks
    __shared__ u64 hrow[68];       // horizontal 5-OR row masks
    __shared__ float wsum[NT / 64];

    const int tid = threadIdx.x;
    const int bz = blockIdx.z;
    const int r0 = blockIdx.y * 64;
    const int c0 = blockIdx.x * 64;
    const float* pimg = pred + (size_t)bz * H_IMG * W_IMG;
    const float* timg = target + (size_t)bz * H_IMG * W_IMG;

    // ---- pred prefetch: 16 px/thread into registers; the loads stream
    // concurrently with stage 0's target reads and have landed long before
    // stage D consumes them. ----
    const int trow = tid >> 2;
    const int tcb = (tid & 3) * 16;
    const float4* pv4 = (const float4*)(pimg + (size_t)(r0 + trow) * W_IMG + (c0 + tcb));
    float4 pf[4];
#pragma unroll
    for (int k = 0; k < 4; ++k) pf[k] = pv4[k];

    // ---- Stage 0 (fused binarize): target halo f32 -> nibble LDS, with
    // edge-replicate clamp. 72 rows x 9 u32-words; word q covers image cols
    // c0-4+8q .. c0+3+8q (two aligned float4 loads for interior words). ----
    for (int t = tid; t < 72 * 9; t += NT) {
        int tr = t / 9, q = t - tr * 9;
        int r = r0 - 4 + tr; r = r < 0 ? 0 : (r > H_IMG - 1 ? H_IMG - 1 : r);
        const float* rowp = timg + (size_t)r * W_IMG;
        int cbase = c0 - 4 + 8 * q;            // multiple of 4 -> 16B aligned
        u32 x;
        if (cbase >= 0 && cbase + 7 <= W_IMG - 1) {
            float4 f0 = *(const float4*)(rowp + cbase);
            float4 f1 = *(const float4*)(rowp + cbase + 4);
            x  = (f0.x > 0.5f ? 0x1u        : 0u)
               | (f0.y > 0.5f ? 0x10u       : 0u)
               | (f0.z > 0.5f ? 0x100u      : 0u)
               | (f0.w > 0.5f ? 0x1000u     : 0u)
               | (f1.x > 0.5f ? 0x10000u    : 0u)
               | (f1.y > 0.5f ? 0x100000u   : 0u)
               | (f1.z > 0.5f ? 0x1000000u  : 0u)
               | (f1.w > 0.5f ? 0x10000000u : 0u);
        } else {
            // only block-col 0 (q==0) and block-col 15 (q==8): replicate cols
            x = 0;
#pragma unroll
            for (int k = 0; k < 8; ++k) {
                int c = cbase + k; c = c < 0 ? 0 : (c > W_IMG - 1 ? W_IMG - 1 : c);
                x |= (rowp[c] > 0.5f ? 1u : 0u) << (4 * k);
            }
        }
        simg[tr][q] = x;
        if (q == 0) { simg[tr][9] = 0; simg[tr][10] = 0; }
    }
    __syncthreads();

    // ---- Stage A: SWAR Sobel -> m + class planes (16 px / task) ----
    for (int t = tid; t < 70 * 6; t += NT) {
        int mrow = t / 6, wi = t - mrow * 6;
        if (wi == 5) { mw[mrow][5] = 0; clw[mrow][5] = 0; continue; }
        u64 Lr[3], Cr[3], Rr[3];
#pragma unroll
        for (int k = 0; k < 3; ++k) {
            int ir = mrow + k;
            u32 a0 = simg[ir][2 * wi], a1 = simg[ir][2 * wi + 1], a2 = simg[ir][2 * wi + 2];
            u64 w0 = (u64)a0 | ((u64)a1 << 32);
            Lr[k] = w0;                                        // col-1
            Cr[k] = (w0 >> 4) | ((u64)(a2 & 0xFu) << 60);      // center
            Rr[k] = (w0 >> 8) | ((u64)(a2 & 0xFFu) << 56);     // col+1
        }
        u64 Px = Rr[0] + (Rr[1] << 1) + Rr[2];
        u64 Nx = Lr[0] + (Lr[1] << 1) + Lr[2];
        u64 Py = Lr[2] + (Cr[2] << 1) + Rr[2];
        u64 Ny = Lr[0] + (Cr[0] << 1) + Rr[0];
        u64 Dbx = (Px + K8) - Nx;                // gx+8 per nibble, no borrows
        u64 Dby = (Py + K8) - Ny;

        u64 mx = (Dbx >> 3) & K1;                // gx >= 0
        u64 mfx = (mx << 4) - mx;
        u64 ax = ((Dbx & K7) & mfx) | (((((~Dbx) & K7) + K1)) & ~mfx);
        u64 my = (Dby >> 3) & K1;
        u64 mfy = (my << 4) - my;
        u64 ay = ((Dby & K7) & mfy) | (((((~Dby) & K7) + K1)) & ~mfy);
        u64 m = ax + ay;                         // <= 6

        u64 ax0 = ax & K1, ax1b = (ax >> 1) & K1, ax2b = (ax >> 2) & K1;
        u64 ay0 = ay & K1, ay1b = (ay >> 1) & K1, ay2b = (ay >> 2) & K1;
        u64 axnz = ax0 | ax1b | ax2b;
        u64 aynz = ay0 | ay1b | ay2b;
        u64 axe1 = ax0 & ~(ax1b | ax2b);
        u64 aye1 = ay0 & ~(ay1b | ay2b);
        u64 axg3 = ax2b | (ax1b & ax0);
        u64 ayg3 = ay2b | (ay1b & ay0);
        u64 horiz = ((K1 & ~aynz) & axnz) | (aye1 & axg3);
        u64 vert  = ((K1 & ~axnz) & aynz) | (axe1 & ayg3);

        u64 gxp = mx & ((Dbx | (Dbx >> 1) | (Dbx >> 2)) & K1);
        u64 gxn = K1 & ~mx;
        u64 gyp = my & ((Dby | (Dby >> 1) | (Dby >> 2)) & K1);
        u64 gyn = K1 & ~my;
        u64 sd = (gxp & gyn) | (gxn & gyp);

        mw[mrow][wi] = m;
        clw[mrow][wi] = horiz | (vert << 1) | (sd << 2);
    }
    __syncthreads();

    // ---- Stage B: SWAR NMS + threshold + interior -> strong bitmasks ----
    for (int t = tid; t < 68 * 5; t += NT) {
        int srow = t / 5, wi = t - srow * 5;
        u16 outm = 0;
        int rr = r0 - 2 + srow;
        if (rr >= 1 && rr <= H_IMG - 2) {
            int ra = srow, rb = srow + 1, rc = srow + 2;
            u64 a0 = mw[ra][wi], a1 = mw[ra][wi + 1];
            u64 b0 = mw[rb][wi], b1 = mw[rb][wi + 1];
            u64 g0 = mw[rc][wi], g1 = mw[rc][wi + 1];
            u64 U  = (a0 >> 4) | (a1 << 60);
            u64 UL = a0;
            u64 UR = (a0 >> 8) | (a1 << 56);
            u64 M  = (b0 >> 4) | (b1 << 60);
            u64 Lf = b0;
            u64 Rg = (b0 >> 8) | (b1 << 56);
            u64 Dn = (g0 >> 4) | (g1 << 60);
            u64 DL = g0;
            u64 DR = (g0 >> 8) | (g1 << 56);

            u64 q0 = clw[rb][wi], q1 = clw[rb][wi + 1];
            u64 CC = (q0 >> 4) | (q1 << 60);
            u64 H8 = (CC & K1) << 3;
            u64 V8 = ((CC >> 1) & K1) << 3;
            u64 S8 = ((CC >> 2) & K1) << 3;

            u64 kH = gt8(M, Lf) & geq8(M, Rg);
            u64 kV = gt8(M, U)  & geq8(M, Dn);
            u64 kA = gt8(M, UR) & geq8(M, DL);
            u64 kB = gt8(M, UL) & geq8(M, DR);
            u64 nHV = K8 & ~(H8 | V8);
            u64 keep = (H8 & kH) | (V8 & kV) | (nHV & S8 & kA) | (nHV & ~S8 & kB);
            u64 nz = ((M | (M >> 1) | (M >> 2)) & K1) << 3;   // m >= 1
            u64 cand = keep & nz;

            int basec = c0 - 2 + 16 * wi;
            int lo = 1 - basec; if (lo < 0) lo = 0;
            int hi = (W_IMG - 2) - basec; if (hi > 15) hi = 15;
            if (lo > hi) cand = 0;
            else cand &= (~0ULL >> ((15 - hi) * 4)) & (~0ULL << (lo * 4));

            u64 x = cand >> 3;
            x = (x | (x >> 3))  & 0x0303030303030303ULL;
            x = (x | (x >> 6))  & 0x000F000F000F000FULL;
            x = (x | (x >> 12)) & 0x000000FF000000FFULL;
            x = (x | (x >> 24));
            outm = (u16)(x & 0xFFFF);
        }
        ssw[srow][wi] = outm;
    }
    __syncthreads();

    // ---- Stage C: horizontal 5-OR over strong row bitmasks ----
    for (int t = tid; t < 68; t += NT) {
        u64 lo = (u64)ssw[t][0] | ((u64)ssw[t][1] << 16) |
                 ((u64)ssw[t][2] << 32) | ((u64)ssw[t][3] << 48);
        u64 hib = (u64)(ssw[t][4] & 0xFu);
        u64 acc = lo;
#pragma unroll
        for (int d = 1; d <= 4; ++d)
            acc |= (lo >> d) | (hib << (64 - d));
        hrow[t] = acc;
    }
    __syncthreads();

    // ---- Stage D: vertical 5-OR + weighted BCE; 16 px / thread ----
    float accv = 0.0f;
    {
        u64 ez64 = hrow[trow] | hrow[trow + 1] | hrow[trow + 2] |
                   hrow[trow + 3] | hrow[trow + 4];
        u64 ezw = ez64 >> tcb;
        int q = (tcb + 4) >> 3;
        u32 ua = simg[trow + 4][q], ub = simg[trow + 4][q + 1], uc = simg[trow + 4][q + 2];
        u64 tb = ((u64)(ua >> 16)) | ((u64)ub << 16) | (((u64)(uc & 0xFFFFu)) << 48);
#pragma unroll
        for (int kk = 0; kk < 4; ++kk) {
            float4 pv = pf[kk];
            float ps[4] = {pv.x, pv.y, pv.z, pv.w};
#pragma unroll
            for (int cc = 0; cc < 4; ++cc) {
                int k = kk * 4 + cc;
                float p = ps[cc];
                float xx = ((tb >> (4 * k)) & 1) ? p : 1.0f - p;
                float lg = fmaxf(__logf(xx), -100.0f);
                float w = ((ezw >> k) & 1) ? 5.0f : 1.0f;
                accv = fmaf(w, -lg, accv);
            }
        }
    }

    for (int off = 32; off > 0; off >>= 1)
        accv += __shfl_down(accv, off);
    int wid = tid >> 6, lane = tid & 63;
    if (lane == 0) wsum[wid] = accv;
    __syncthreads();
    if (tid == 0) {
        int bi = (blockIdx.z * gridDim.y + blockIdx.y) * gridDim.x + blockIdx.x;
        partials[bi] = wsum[0] + wsum[1] + wsum[2] + wsum[3];
    }
}

__global__ __launch_bounds__(256)
void finalize_kernel(const float* __restrict__ partials, float* __restrict__ out,
                     int nblocks, double invN)
{
    __shared__ double ws[4];
    double s = 0.0;
    for (int i = threadIdx.x; i < nblocks; i += 256) s += (double)partials[i];
    for (int off = 32; off > 0; off >>= 1) s += __shfl_down(s, off);
    int wid = threadIdx.x >> 6, lane = threadIdx.x & 63;
    if (lane == 0) ws[wid] = s;
    __syncthreads();
    if (threadIdx.x == 0) out[0] = (float)((ws[0] + ws[1] + ws[2] + ws[3]) * invN);
}

extern "C" void kernel_launch(void* const* d_in, const int* in_sizes, int n_in,
                              void* d_out, int out_size, void* d_ws, size_t ws_size,
                              hipStream_t stream)
{
    (void)n_in; (void)out_size; (void)ws_size;
    const float* pred   = (const float*)d_in[0];
    const float* target = (const float*)d_in[1];
    const int N = in_sizes[0];
    const int B = N / (H_IMG * W_IMG);

    // ws layout: [0,16KB) per-block partials
    float* partials = (float*)d_ws;

    dim3 grid(W_IMG / 64, H_IMG / 64, B);
    int nblocks = (W_IMG / 64) * (H_IMG / 64) * B;
    edge_loss_kernel<<<grid, NT, 0, stream>>>(pred, target, partials);
    finalize_kernel<<<1, 256, 0, stream>>>(partials, (float*)d_out, nblocks,
                                           1.0 / (double)N);
}

// Round 2
// 45.784 us; speedup vs baseline: 1.0594x; 1.0594x over previous
//
#include <hip/hip_runtime.h>
#include <math.h>

// EdgeAwareLoss — round 5: bit-sliced Canny (64 px per u64 op).
//
// Exactness vs the JAX reference (nibble version validated absmax 0.0 r1-r3;
// this version computes the SAME integers via bit-plane arithmetic):
//  - img = (t>0.5)*255, integer Sobel => m multiple of 255 => weak==strong,
//    hysteresis is an immediate fixed point => strong == cand.
//  - In 255-units: gx,gy in [-4,4], m = |gx|+|gy| <= 6 (3 bit-planes).
//  - horiz (ay < ax*tan22.5): ay==0&&ax>=1 || ay==1&&ax>=3
//    vert  (ay > ax*tan67.5): ax==0&&ay>=1 || ax==1&&ay>=3
//  - NMS trick: for row-horizontal compare, P(j) = m[j] > m[j-1] gives
//    kH = P & ~(P>>1)  (since ge(m,right)(j) = ~(m[j+1]>m[j]) = ~P(j+1)).
//  - bce = -max(log(t?p:1-p), -100); 1-p exact for p>=0.5 (Sterbenz).
//
// Geometry: tile 32 cols x 64 rows per block; frame bit j = col c0-4+j,
// j in [0,40) -> all planes are single u64 (bits >=40 are garbage, masked
// downstream). m valid j=1..38, cand valid j=2..37, tile j=4..35.
//
// r4 post-mortem: fused f32 binarize regressed (VALU-bound kernel, 42% busy).
// r5 cuts the dominant VALU: nibble-SWAR (16 px/op) -> bit-planes (64 px/op),
// ~3x fewer wave-issues in Sobel+NMS. Binarize kernel back to r3's verbatim
// (its packing is already plain bit order: bit b of word t = px 32t+b).

typedef unsigned long long u64;
typedef unsigned int u32;

#define NT 128
#define H_IMG 1024
#define W_IMG 1024
#define WPR 32                 // packed u32 words per image row

// ---- pre-pass: binarize target to 1 bit/px (verbatim r3; plain bit order) --
__global__ __launch_bounds__(256)
void binarize_kernel(const float* __restrict__ target, u32* __restrict__ packed,
                     int nwords)
{
    int t = blockIdx.x * 256 + threadIdx.x;
    if (t >= nwords) return;
    const float4* src = (const float4*)target + (size_t)t * 8;
    u32 v = 0;
#pragma unroll
    for (int k = 0; k < 8; ++k) {
        float4 f = src[k];
        v |= (f.x > 0.5f ? 1u : 0u) << (4 * k);
        v |= (f.y > 0.5f ? 2u : 0u) << (4 * k);
        v |= (f.z > 0.5f ? 4u : 0u) << (4 * k);
        v |= (f.w > 0.5f ? 8u : 0u) << (4 * k);
    }
    packed[t] = v;
}

// unsigned 3-bit bit-sliced compare: returns plane of (a > b)
__device__ __forceinline__ u64 gt3(u64 a2, u64 a1, u64 a0,
                                   u64 b2, u64 b1, u64 b0)
{
    u64 e2 = ~(a2 ^ b2), g2 = a2 & ~b2;
    u64 e1 = ~(a1 ^ b1), g1 = a1 & ~b1;
    u64 g0 = a0 & ~b0;
    return g2 | (e2 & (g1 | (e1 & g0)));
}

__global__ __launch_bounds__(NT)
void edge_loss_kernel(const float* __restrict__ pred,
                      const u32* __restrict__ packed,
                      float* __restrict__ partials)
{
    __shared__ u64 bl[72];                    // binarized target, bit j = col c0-4+j
    __shared__ u64 m0[70], m1[70], m2[70];    // m bit-planes, row tr = idx+1
    __shared__ u64 hz[70], vt[70], sdp[70];   // class planes (center rows)
    __shared__ u64 hr[68];                    // horizontal 5-OR of cand, row tr = idx+2
    __shared__ float wsum[2];

    const int tid = threadIdx.x;
    const int bx = blockIdx.x;
    const int bz = blockIdx.z;
    const int r0 = blockIdx.y * 64;
    const int c0 = bx * 32;
    const float* pimg = pred + (size_t)bz * H_IMG * W_IMG;
    const u32* pb = packed + (size_t)bz * H_IMG * WPR;

    // ---- pred prefetch: 16 px/thread (4 float4); streams during stages 0-B
    const int trow = tid >> 1;
    const int tcb = (tid & 1) * 16;
    const float4* pv4 = (const float4*)(pimg + (size_t)(r0 + trow) * W_IMG + (c0 + tcb));
    float4 pf[4];
#pragma unroll
    for (int k = 0; k < 4; ++k) pf[k] = pv4[k];

    // ---- Stage 0: packed bits -> 40-bit row windows, edge-replicate clamp
    if (tid < 72) {
        int r = r0 - 4 + tid; r = r < 0 ? 0 : (r > H_IMG - 1 ? H_IMG - 1 : r);
        const u32* prow = pb + (size_t)r * WPR;
        u32 wB = prow[bx];
        u32 wA = (bx > 0) ? prow[bx - 1] : ((wB & 1u) ? ~0u : 0u);
        u32 wC = (bx + 1 < WPR) ? prow[bx + 1] : ((wB >> 31) ? ~0u : 0u);
        bl[tid] = (u64)(wA >> 28) | ((u64)wB << 4) | ((u64)(wC & 0xFu) << 36);
    }
    __syncthreads();

    // ---- Stage A: bit-sliced Sobel -> m planes + class planes (rows 1..70)
    if (tid < 70) {
        const int tr = tid + 1;
        u64 A = bl[tr - 1], Bq = bl[tr], C = bl[tr + 1];
        u64 AL = A << 1, AR = A >> 1;
        u64 BL = Bq << 1, BR = Bq >> 1;
        u64 CL = C << 1, CR = C >> 1;

        // Px = AR + 2*BR + CR (0..4, 3 planes); Nx = AL + 2*BL + CL
        u64 sx = AR ^ CR, cxk = AR & CR;
        u64 Px1 = BR ^ cxk, Px2 = BR & cxk;
        u64 sn = AL ^ CL, cnk = AL & CL;
        u64 Nx1 = BL ^ cnk, Nx2 = BL & cnk;
        // D = Px - Nx as 4-bit two's complement (Px + ~Nx + 1)
        u64 d0 = sx ^ sn;
        u64 ca = sx | ~sn;
        u64 nb1 = ~Nx1, t1 = Px1 ^ nb1, d1 = t1 ^ ca;
        u64 cb = (Px1 & nb1) | (ca & t1);
        u64 nb2 = ~Nx2, t2 = Px2 ^ nb2, d2 = t2 ^ cb;
        u64 cc = (Px2 & nb2) | (cb & t2);
        u64 sgx = ~cc;                         // gx < 0
        // ax = |gx| (verified identities: d1^n1=d0, d2^n2=d0|d1)
        u64 ax0 = d0;
        u64 ax1 = d1 ^ (sgx & d0);
        u64 ax2 = d2 ^ (sgx & (d0 | d1));

        // Py = CL + 2*C + CR; Ny = AL + 2*A + AR
        u64 sy = CL ^ CR, cyk = CL & CR;
        u64 Py1 = C ^ cyk, Py2 = C & cyk;
        u64 sm = AL ^ AR, cmk = AL & AR;
        u64 Ny1 = A ^ cmk, Ny2 = A & cmk;
        u64 e0 = sy ^ sm;
        u64 ka = sy | ~sm;
        u64 mb1 = ~Ny1, u1 = Py1 ^ mb1, f1 = u1 ^ ka;
        u64 kb = (Py1 & mb1) | (ka & u1);
        u64 mb2 = ~Ny2, u2 = Py2 ^ mb2, f2 = u2 ^ kb;
        u64 kc = (Py2 & mb2) | (kb & u2);
        u64 sgy = ~kc;                         // gy < 0
        u64 ay0 = e0;
        u64 ay1 = f1 ^ (sgy & e0);
        u64 ay2 = f2 ^ (sgy & (e0 | f1));

        // m = ax + ay (<= 6, no carry out of bit2)
        u64 s0 = ax0 ^ ay0, q0 = ax0 & ay0;
        u64 tt = ax1 ^ ay1, s1 = tt ^ q0;
        u64 q1 = (ax1 & ay1) | (q0 & tt);
        u64 s2 = ax2 ^ ay2 ^ q1;
        m0[tid] = s0; m1[tid] = s1; m2[tid] = s2;

        // classes
        u64 ax12 = ax1 | ax2, axnz = ax0 | ax12;
        u64 axe1 = ax0 & ~ax12, axg3 = ax2 | (ax1 & ax0);
        u64 ay12 = ay1 | ay2, aynz = ay0 | ay12;
        u64 aye1 = ay0 & ~ay12, ayg3 = ay2 | (ay1 & ay0);
        hz[tid] = (axnz & ~aynz) | (aye1 & axg3);
        vt[tid] = (aynz & ~axnz) | (axe1 & ayg3);
        u64 gxp = axnz & ~sgx, gyp = aynz & ~sgy;
        sdp[tid] = (gxp & sgy) | (sgx & gyp);
    }
    __syncthreads();

    // ---- Stage B: bit-sliced NMS + threshold + interior; fused horiz 5-OR
    if (tid < 68) {
        const int i = tid + 1;                 // m-plane index of center row tr=tid+2
        u64 M0 = m0[i], M1 = m1[i], M2 = m2[i];
        u64 U0 = m0[i - 1], U1 = m1[i - 1], U2 = m2[i - 1];
        u64 D0 = m0[i + 1], D1 = m1[i + 1], D2 = m2[i + 1];
        u64 H = hz[i], V = vt[i], S = sdp[i];

        u64 P = gt3(M2, M1, M0, M2 << 1, M1 << 1, M0 << 1);   // m > left
        u64 kH = P & ~(P >> 1);                               // & (m >= right)
        u64 gMU = gt3(M2, M1, M0, U2, U1, U0);
        u64 gDM = gt3(D2, D1, D0, M2, M1, M0);
        u64 kV = gMU & ~gDM;
        u64 gMUR = gt3(M2, M1, M0, U2 >> 1, U1 >> 1, U0 >> 1);
        u64 gDLM = gt3(D2 << 1, D1 << 1, D0 << 1, M2, M1, M0);
        u64 kA = gMUR & ~gDLM;                                // (m>ur)&(m>=dl)
        u64 gMUL = gt3(M2, M1, M0, U2 << 1, U1 << 1, U0 << 1);
        u64 gDRM = gt3(D2 >> 1, D1 >> 1, D0 >> 1, M2, M1, M0);
        u64 kB = gMUL & ~gDRM;                                // (m>ul)&(m>=dr)

        u64 nHV = ~(H | V);
        u64 keep = (H & kH) | (V & kV) | (nHV & ((S & kA) | (~S & kB)));
        u64 nz = M0 | M1 | M2;                                // m >= 1 (m>50/255)
        u64 colmask = (~0ULL << ((bx == 0) ? 5 : 2)) &
                      (~0ULL >> (63 - ((bx == 31) ? 34 : 37)));
        u64 cand = keep & nz & colmask;
        int rr = r0 - 2 + tid;
        if (rr < 1 || rr > H_IMG - 2) cand = 0;
        hr[tid] = cand | (cand << 1) | (cand << 2) | (cand >> 1) | (cand >> 2);
    }
    __syncthreads();

    // ---- Stage D: vertical 5-OR + weighted BCE; 16 px / thread ----
    float accv = 0.0f;
    {
        u64 ez = hr[trow] | hr[trow + 1] | hr[trow + 2] |
                 hr[trow + 3] | hr[trow + 4];
        u32 ezw = (u32)(ez >> (tcb + 4));
        u32 tb = (u32)(bl[trow + 4] >> (tcb + 4));
#pragma unroll
        for (int kk = 0; kk < 4; ++kk) {
            float4 pv = pf[kk];
            float ps[4] = {pv.x, pv.y, pv.z, pv.w};
#pragma unroll
            for (int cc = 0; cc < 4; ++cc) {
                int k = kk * 4 + cc;
                float p = ps[cc];
                float xx = ((tb >> k) & 1) ? p : 1.0f - p;
                float lg = fmaxf(__logf(xx), -100.0f);
                float w = ((ezw >> k) & 1) ? 5.0f : 1.0f;
                accv = fmaf(w, -lg, accv);
            }
        }
    }

    for (int off = 32; off > 0; off >>= 1)
        accv += __shfl_down(accv, off);
    int wid = tid >> 6, lane = tid & 63;
    if (lane == 0) wsum[wid] = accv;
    __syncthreads();
    if (tid == 0) {
        int bi = (blockIdx.z * gridDim.y + blockIdx.y) * gridDim.x + blockIdx.x;
        partials[bi] = wsum[0] + wsum[1];
    }
}

__global__ __launch_bounds__(256)
void finalize_kernel(const float* __restrict__ partials, float* __restrict__ out,
                     int nblocks, double invN)
{
    __shared__ double ws[4];
    double s = 0.0;
    for (int i = threadIdx.x; i < nblocks; i += 256) s += (double)partials[i];
    for (int off = 32; off > 0; off >>= 1) s += __shfl_down(s, off);
    int wid = threadIdx.x >> 6, lane = threadIdx.x & 63;
    if (lane == 0) ws[wid] = s;
    __syncthreads();
    if (threadIdx.x == 0) out[0] = (float)((ws[0] + ws[1] + ws[2] + ws[3]) * invN);
}

extern "C" void kernel_launch(void* const* d_in, const int* in_sizes, int n_in,
                              void* d_out, int out_size, void* d_ws, size_t ws_size,
                              hipStream_t stream)
{
    (void)n_in; (void)out_size; (void)ws_size;
    const float* pred   = (const float*)d_in[0];
    const float* target = (const float*)d_in[1];
    const int N = in_sizes[0];
    const int B = N / (H_IMG * W_IMG);

    // ws layout: [0,32KB) per-block partials; [32KB, 32KB+2MB) packed bits
    float* partials = (float*)d_ws;
    u32* packed = (u32*)((char*)d_ws + 32768);
    const int nwords = B * H_IMG * WPR;          // 524288 (2 MB)

    binarize_kernel<<<(nwords + 255) / 256, 256, 0, stream>>>(target, packed, nwords);

    dim3 grid(W_IMG / 32, H_IMG / 64, B);
    int nblocks = (W_IMG / 32) * (H_IMG / 64) * B;
    edge_loss_kernel<<<grid, NT, 0, stream>>>(pred, packed, partials);
    finalize_kernel<<<1, 256, 0, stream>>>(partials, (float*)d_out, nblocks,
                                           1.0 / (double)N);
}